// Round 3
// baseline (1514.511 us; speedup 1.0000x reference)
//
#include <hip/hip_runtime.h>
#include <hip/hip_fp16.h>
#include <stdint.h>

#define LT 512   // timesteps
#define NB 512   // batch
#define DI 128   // input dim
#define DH 128   // hidden dim
#define G4 512   // 4*H gates
#define MROWS (LT * NB)
#define L2E 1.44269504f

typedef _Float16 f16;
typedef __attribute__((ext_vector_type(2))) _Float16 f16x2;
typedef __attribute__((ext_vector_type(4))) _Float16 f16x4;
typedef __attribute__((ext_vector_type(8))) _Float16 f16x8;
typedef __attribute__((ext_vector_type(4))) float floatx4;

__device__ __forceinline__ float dot2f(uint32_t a, uint32_t b, float c) {
#if __has_builtin(__builtin_amdgcn_fdot2)
    return __builtin_amdgcn_fdot2(__builtin_bit_cast(f16x2, a),
                                  __builtin_bit_cast(f16x2, b), c, false);
#else
    f16x2 pa = __builtin_bit_cast(f16x2, a);
    f16x2 pb = __builtin_bit_cast(f16x2, b);
    return c + (float)pa.x * (float)pb.x + (float)pa.y * (float)pb.y;
#endif
}

__device__ __forceinline__ uint32_t pack2(float x, float y) {
    f16x2 p; p.x = (_Float16)x; p.y = (_Float16)y;
    return __builtin_bit_cast(uint32_t, p);
}
__device__ __forceinline__ float rcpf(float v) { return __builtin_amdgcn_rcpf(v); }
__device__ __forceinline__ float exp2f_(float v) { return __builtin_amdgcn_exp2f(v); }

__device__ __forceinline__ float sigm(float v) { return 1.f / (1.f + __expf(-v)); }
__device__ __forceinline__ float tanh_(float v) {
    float a = fabsf(v);
    float e = __expf(-2.f * a);
    float r = (1.f - e) / (1.f + e);
    return v < 0.f ? -r : r;
}

// ============================================================================
// Kernel 1: gxT[t][gate][n] = s_gate * sum_k x[t,n][k] * Wih[gate][k]  (f16)
// s_gate = -log2e for i/f/o gates, +2log2e for g gate (pre-scaled exp2 args).
// Tile: 128 rows (one t, 128 n) x 256 gates. LDS transpose -> coalesced stores.
// ============================================================================
__launch_bounds__(512, 2)
__global__ void gemm_xgates_T(const float* __restrict__ x,
                              const float* __restrict__ Wih,
                              f16* __restrict__ gxT)
{
    __shared__ uint4 wx[128 * 16];     // 32 KB A-stage (XOR-swizzled frags)
    __shared__ f16 T[128][136];        // 34.8 KB transpose buffer (+8 pad)
    const int tid = threadIdx.x;
    const int bm  = blockIdx.x >> 1;
    const int gh  = blockIdx.x & 1;
    const size_t rowbase = (size_t)bm * 128;
    const int t  = (int)(rowbase >> 9);
    const int n0 = (int)(rowbase & 511);

    // ---- stage x-tile -> LDS f16 frags ----
    {
        const float4* src = (const float4*)(x + rowbase * DI) + (size_t)tid * 8;
#pragma unroll
        for (int i = 0; i < 4; ++i) {
            float4 a = src[2 * i];
            float4 b = src[2 * i + 1];
            uint4 u;
            u.x = pack2(a.x, a.y); u.y = pack2(a.z, a.w);
            u.z = pack2(b.x, b.y); u.w = pack2(b.z, b.w);
            int flat = tid * 4 + i;
            int row  = flat >> 4;
            int m    = flat & 15;
            wx[row * 16 + (m ^ (row & 15))] = u;
        }
    }

    const int lane = tid & 63;
    const int w    = tid >> 6;
    const int l16  = lane & 15;
    const int quad = lane >> 4;

    // ---- B-frags (Wih rows), scaled by per-gate exp2 constant ----
    f16x8 bfrag[2][4];
#pragma unroll
    for (int p = 0; p < 2; ++p) {
        int gate = gh * 256 + (w * 2 + p) * 16 + l16;
        float s = ((gate >> 7) == 2) ? 2.f * L2E : -L2E;
        const float4* wp = (const float4*)(Wih + (size_t)gate * DI);
#pragma unroll
        for (int kc = 0; kc < 4; ++kc) {
            float4 a = wp[kc * 8 + quad * 2];
            float4 b = wp[kc * 8 + quad * 2 + 1];
            uint4 u;
            u.x = pack2(s * a.x, s * a.y); u.y = pack2(s * a.z, s * a.w);
            u.z = pack2(s * b.x, s * b.y); u.w = pack2(s * b.z, s * b.w);
            bfrag[p][kc] = __builtin_bit_cast(f16x8, u);
        }
    }
    __syncthreads();

    // ---- MFMA: keep all accs in regs (8 row-sets x 2 gate-tiles) ----
    floatx4 acc[8][2];
#pragma unroll
    for (int rs = 0; rs < 8; ++rs) {
        f16x8 afrag[4];
        int row = rs * 16 + l16;
#pragma unroll
        for (int kc = 0; kc < 4; ++kc) {
            int m = kc * 4 + quad;
            afrag[kc] = __builtin_bit_cast(f16x8, wx[row * 16 + (m ^ (row & 15))]);
        }
        floatx4 a0 = {0.f, 0.f, 0.f, 0.f};
        floatx4 a1 = {0.f, 0.f, 0.f, 0.f};
#pragma unroll
        for (int kc = 0; kc < 4; ++kc) {
            a0 = __builtin_amdgcn_mfma_f32_16x16x32_f16(afrag[kc], bfrag[0][kc], a0, 0, 0, 0);
            a1 = __builtin_amdgcn_mfma_f32_16x16x32_f16(afrag[kc], bfrag[1][kc], a1, 0, 0, 0);
        }
        acc[rs][0] = a0;
        acc[rs][1] = a1;
    }

    // ---- transpose via LDS, two 128-gate halves; coalesced b128 stores ----
    for (int hs = 0; hs < 2; ++hs) {
        __syncthreads();
        if ((w >> 2) == hs) {
#pragma unroll
            for (int rs = 0; rs < 8; ++rs) {
#pragma unroll
                for (int p = 0; p < 2; ++p) {
                    int tg = (w & 3) * 32 + p * 16 + l16;   // local gate in half
                    f16x4 v;
                    v[0] = (f16)acc[rs][p][0];
                    v[1] = (f16)acc[rs][p][1];
                    v[2] = (f16)acc[rs][p][2];
                    v[3] = (f16)acc[rs][p][3];
                    *(f16x4*)&T[tg][rs * 16 + quad * 4] = v;
                }
            }
        }
        __syncthreads();
#pragma unroll
        for (int pass = 0; pass < 4; ++pass) {
            int flat = pass * 512 + tid;
            int grow = flat >> 4;
            int seg  = flat & 15;
            f16x8 v = *(const f16x8*)&T[grow][seg * 8];
            int gate = gh * 256 + hs * 128 + grow;
            *(f16x8*)(gxT + ((size_t)t * G4 + gate) * NB + n0 + seg * 8) = v;
        }
    }
}

// ============================================================================
// Kernel 2: recurrence via MFMA. 32 blocks x 512 thr; block owns 16 batch rows.
// Wave w owns gate cols j in [16w,16w+16) for ALL FOUR gates -> i,f,g,o for a
// given (row,j) land in the same lane's accs; update is pure per-lane VALU.
// h (masked, f16) round-trips through a 4.3 KB LDS buffer as MFMA A-operand.
// ============================================================================
__launch_bounds__(512, 1)
__global__ void lstm_rec_mfma(const f16* __restrict__ gxT,    // [L][512][N]
                              const float* __restrict__ hc0,  // [N][2H]
                              const int*   __restrict__ isini,// [L][N]
                              const float* __restrict__ Whh,  // [4H][H]
                              const float* __restrict__ bih,
                              const float* __restrict__ bhh,
                              float* __restrict__ out)        // [L][N][H] ++ [N][2H]
{
    const int tid  = threadIdx.x;
    const int lane = tid & 63;
    const int w    = tid >> 6;
    const int l16  = lane & 15;
    const int quad = lane >> 4;
    const int n0   = blockIdx.x * 16;
    const int j    = w * 16 + l16;

    __shared__ f16 hbuf[16][136];   // padded: stride 272 B (16B-aligned, 2-way banks)

    // ---- Whh B-frags (scaled) + scaled biases, resident all 512 steps ----
    f16x8 bfrag[4][4];
    float bias[4];
    int   gc[4];
#pragma unroll
    for (int q = 0; q < 4; ++q) {
        gc[q] = q * 128 + j;
        float s = (q == 2) ? 2.f * L2E : -L2E;
        const float4* wp = (const float4*)(Whh + (size_t)gc[q] * DH);
#pragma unroll
        for (int kc = 0; kc < 4; ++kc) {
            float4 a = wp[kc * 8 + quad * 2];
            float4 b = wp[kc * 8 + quad * 2 + 1];
            uint4 u;
            u.x = pack2(s * a.x, s * a.y); u.y = pack2(s * a.z, s * a.w);
            u.z = pack2(s * b.x, s * b.y); u.w = pack2(s * b.z, s * b.w);
            bfrag[q][kc] = __builtin_bit_cast(f16x8, u);
        }
        bias[q] = s * (bih[gc[q]] + bhh[gc[q]]);
    }

    // ---- init state ----
    float cst[4], mc[4], hv[4];
    {
        int mi[4];
        *(int4*)mi = *(const int4*)(isini + n0 + quad * 4);
#pragma unroll
        for (int r = 0; r < 4; ++r) {
            int n = n0 + quad * 4 + r;
            cst[r] = hc0[(size_t)n * (2 * DH) + DH + j];
            mc[r]  = 1.f - (float)mi[r];
            hv[r]  = 0.f;
        }
    }
#pragma unroll
    for (int e = 0; e < 4; ++e) {
        int idx = tid * 4 + e;
        int row = idx >> 7;
        int k   = idx & 127;
        float m0 = 1.f - (float)isini[n0 + row];
        hbuf[row][k] = (f16)(hc0[(size_t)(n0 + row) * (2 * DH) + k] * m0);
    }

    // gx prefetch for t=0
    f16x4 gxc[4];
#pragma unroll
    for (int q = 0; q < 4; ++q)
        gxc[q] = *(const f16x4*)(gxT + (size_t)gc[q] * NB + n0 + quad * 4);
    __syncthreads();

    for (int t = 0; t < LT; ++t) {
        // prefetch next step's gx + masks
        int tn = (t + 1 < LT) ? (t + 1) : (LT - 1);
        f16x4 gxn[4];
#pragma unroll
        for (int q = 0; q < 4; ++q)
            gxn[q] = *(const f16x4*)(gxT + ((size_t)tn * G4 + gc[q]) * NB + n0 + quad * 4);
        int mi[4];
        *(int4*)mi = *(const int4*)(isini + (size_t)tn * NB + n0 + quad * 4);

        // A-frags from LDS: m = l16, k = kc*32 + quad*8 + e
        f16x8 af[4];
        const char* hb = (const char*)hbuf + l16 * 272 + quad * 16;
#pragma unroll
        for (int kc = 0; kc < 4; ++kc)
            af[kc] = *(const f16x8*)(hb + kc * 64);

        floatx4 acc[4];
#pragma unroll
        for (int q = 0; q < 4; ++q) acc[q] = (floatx4){0.f, 0.f, 0.f, 0.f};
#pragma unroll
        for (int kc = 0; kc < 4; ++kc) {
#pragma unroll
            for (int q = 0; q < 4; ++q)
                acc[q] = __builtin_amdgcn_mfma_f32_16x16x32_f16(af[kc], bfrag[q][kc], acc[q], 0, 0, 0);
        }

        // per-lane cell update: rows quad*4+r, col j
#pragma unroll
        for (int r = 0; r < 4; ++r) {
            float p0 = acc[0][r] + bias[0] + (float)gxc[0][r];   // i (pre * -log2e)
            float p1 = acc[1][r] + bias[1] + (float)gxc[1][r];   // f
            float p2 = acc[2][r] + bias[2] + (float)gxc[2][r];   // g (pre * 2log2e)
            float p3 = acc[3][r] + bias[3] + (float)gxc[3][r];   // o
            float ei = exp2f_(p0);
            float ef = exp2f_(p1);
            float eg = exp2f_(fminf(p2, 126.f));
            float eo = exp2f_(p3);
            // sigm(i)*tanh(g) = (eg-1) / ((1+ei)(1+eg))
            float igg = (eg - 1.f) * rcpf((1.f + ei) * (1.f + eg));
            float c = (mc[r] * cst[r]) * rcpf(1.f + ef) + igg;
            cst[r] = c;
            float e2c = exp2f_(fminf(2.f * L2E * c, 126.f));
            // sigm(o)*tanh(c) = (e2c-1) / ((1+eo)(1+e2c))
            hv[r] = (e2c - 1.f) * rcpf((1.f + eo) * (1.f + e2c));
            out[((size_t)t * NB + n0 + quad * 4 + r) * DH + j] = hv[r];
        }

        __syncthreads();   // all A-reads done before h overwrite
#pragma unroll
        for (int r = 0; r < 4; ++r) {
            float mn = 1.f - (float)mi[r];
            hbuf[quad * 4 + r][j] = (f16)(hv[r] * mn);  // masked for step t+1
            mc[r] = mn;
        }
#pragma unroll
        for (int q = 0; q < 4; ++q) gxc[q] = gxn[q];
        __syncthreads();   // new h visible
    }

    size_t base = (size_t)LT * NB * DH;
#pragma unroll
    for (int r = 0; r < 4; ++r) {
        int n = n0 + quad * 4 + r;
        out[base + (size_t)n * (2 * DH) + j]      = hv[r];
        out[base + (size_t)n * (2 * DH) + DH + j] = cst[r];
    }
}

// ============================================================================
// Fallback (round-1 kernel, verified) if ws too small.
// ============================================================================
__launch_bounds__(512, 2)
__global__ void lstm_fused(const float* __restrict__ x,
                           const float* __restrict__ hc0,
                           const int*   __restrict__ isini,
                           const float* __restrict__ Wih,
                           const float* __restrict__ Whh,
                           const float* __restrict__ bih,
                           const float* __restrict__ bhh,
                           float* __restrict__ out)
{
    const int g   = threadIdx.x;
    const int n0  = blockIdx.x * 2;

    __shared__ __align__(16) f16   sh_h[2][DH];
    __shared__ __align__(16) f16   sh_x[2][2][DI];
    __shared__ __align__(16) float sh_gates[2][G4];

    uint32_t wih[64], whh[64];
    {
        const float4* wi = (const float4*)(Wih + (size_t)g * DI);
        const float4* wh = (const float4*)(Whh + (size_t)g * DI);
#pragma unroll
        for (int i = 0; i < 32; ++i) {
            float4 a = wi[i];
            wih[2 * i]     = pack2(a.x, a.y);
            wih[2 * i + 1] = pack2(a.z, a.w);
            float4 b = wh[i];
            whh[2 * i]     = pack2(b.x, b.y);
            whh[2 * i + 1] = pack2(b.z, b.w);
        }
    }
    const float bias = bih[g] + bhh[g];
    const int row = (threadIdx.x >> 7) & 1;
    const int j   = threadIdx.x & 127;
    const int n   = n0 + row;

    float cval = 0.f, hval = 0.f;

    if (threadIdx.x < 256) {
        cval = hc0[(size_t)n * (2 * DH) + DH + j];
        sh_h[row][j] = (f16)hc0[(size_t)n * (2 * DH) + j];
    } else {
        sh_x[0][row][j] = (f16)x[((size_t)0 * NB + n) * DI + j];
    }
    __syncthreads();

    for (int t = 0; t < LT; ++t) {
        const float m0 = 1.f - (float)isini[(size_t)t * NB + n0];
        const float m1 = 1.f - (float)isini[(size_t)t * NB + n0 + 1];

        float xpre = 0.f;
        if (threadIdx.x >= 256) {
            int tp = (t + 1 < LT) ? (t + 1) : (LT - 1);
            xpre = x[((size_t)tp * NB + n) * DI + j];
        }

        const uint4* xp0 = (const uint4*)&sh_x[t & 1][0][0];
        const uint4* xp1 = (const uint4*)&sh_x[t & 1][1][0];
        const uint4* hp0 = (const uint4*)&sh_h[0][0];
        const uint4* hp1 = (const uint4*)&sh_h[1][0];

        float ax0 = 0.f, ax0b = 0.f, ah0 = 0.f, ah0b = 0.f;
        float ax1 = 0.f, ax1b = 0.f, ah1 = 0.f, ah1b = 0.f;
#pragma unroll
        for (int i = 0; i < 16; ++i) {
            uint4 xv0 = xp0[i];
            uint4 xv1 = xp1[i];
            uint4 hv0 = hp0[i];
            uint4 hv1 = hp1[i];
            ax0  = dot2f(xv0.x, wih[4 * i + 0], ax0);
            ax0b = dot2f(xv0.y, wih[4 * i + 1], ax0b);
            ax0  = dot2f(xv0.z, wih[4 * i + 2], ax0);
            ax0b = dot2f(xv0.w, wih[4 * i + 3], ax0b);
            ah0  = dot2f(hv0.x, whh[4 * i + 0], ah0);
            ah0b = dot2f(hv0.y, whh[4 * i + 1], ah0b);
            ah0  = dot2f(hv0.z, whh[4 * i + 2], ah0);
            ah0b = dot2f(hv0.w, whh[4 * i + 3], ah0b);
            ax1  = dot2f(xv1.x, wih[4 * i + 0], ax1);
            ax1b = dot2f(xv1.y, wih[4 * i + 1], ax1b);
            ax1  = dot2f(xv1.z, wih[4 * i + 2], ax1);
            ax1b = dot2f(xv1.w, wih[4 * i + 3], ax1b);
            ah1  = dot2f(hv1.x, whh[4 * i + 0], ah1);
            ah1b = dot2f(hv1.y, whh[4 * i + 1], ah1b);
            ah1  = dot2f(hv1.z, whh[4 * i + 2], ah1);
            ah1b = dot2f(hv1.w, whh[4 * i + 3], ah1b);
        }
        sh_gates[0][g] = bias + (ax0 + ax0b) + m0 * (ah0 + ah0b);
        sh_gates[1][g] = bias + (ax1 + ax1b) + m1 * (ah1 + ah1b);

        __syncthreads();

        if (threadIdx.x < 256) {
            float ig = sh_gates[row][j];
            float fg = sh_gates[row][128 + j];
            float gg = sh_gates[row][256 + j];
            float og = sh_gates[row][384 + j];
            float m  = row ? m1 : m0;
            float cc = m * cval;
            cc   = sigm(fg) * cc + sigm(ig) * tanh_(gg);
            hval = sigm(og) * tanh_(cc);
            cval = cc;
            out[((size_t)t * NB + n) * DH + j] = hval;
            sh_h[row][j] = (f16)hval;
        } else {
            sh_x[(t + 1) & 1][row][j] = (f16)xpre;
        }
        __syncthreads();
    }

    if (threadIdx.x < 256) {
        size_t base = (size_t)LT * NB * DH;
        out[base + (size_t)n * (2 * DH) + j]      = hval;
        out[base + (size_t)n * (2 * DH) + DH + j] = cval;
    }
}

extern "C" void kernel_launch(void* const* d_in, const int* in_sizes, int n_in,
                              void* d_out, int out_size, void* d_ws, size_t ws_size,
                              hipStream_t stream) {
    const float* x     = (const float*)d_in[0];
    const float* hc0   = (const float*)d_in[1];
    const int*   isini = (const int*)d_in[2];
    const float* Wih   = (const float*)d_in[3];
    const float* Whh   = (const float*)d_in[4];
    const float* bih   = (const float*)d_in[5];
    const float* bhh   = (const float*)d_in[6];
    float* out = (float*)d_out;

    const size_t need = (size_t)MROWS * G4 * sizeof(f16);   // 268 MB
    if (ws_size >= need) {
        f16* gxT = (f16*)d_ws;
        gemm_xgates_T<<<dim3((MROWS / 128) * 2), dim3(512), 0, stream>>>(x, Wih, gxT);
        lstm_rec_mfma<<<dim3(NB / 16), dim3(512), 0, stream>>>(
            gxT, hc0, isini, Whh, bih, bhh, out);
    } else {
        lstm_fused<<<dim3(NB / 2), dim3(512), 0, stream>>>(
            x, hc0, isini, Wih, Whh, bih, bhh, out);
    }
}